// Round 23
// baseline (577.180 us; speedup 1.0000x reference)
//
#include <hip/hip_runtime.h>
#include <hip/hip_bf16.h>
#include <math.h>

// OmniAttentionMechanism: flex-attention, mixed t2i/lm/mmu mask.
// B=6 (b0,b1: t2i pe=80/100; b2,b3: lm; b4,b5: mmu kv<1027), H=16, S=1280, D=64. fp32 I/O.
//
// Round 23 (on R22 green, 93us): KV-SPLIT x2 (split-K analog).
//   R22 confirmed: setprio fences load-bearing; mask/VALU shaving exhausted;
//   occupancy pinned ~18% with waves issuing ~24% of cycles -> chain+drain bound.
//   No-max softmax is LINEAR in kv -> split each item's needed tiles by parity
//   across 2 blocks (grid 1920; longest serial chain 20->10 tiles; launch
//   residency ~24 waves/CU). Last-finisher merge via per-item flag
//   (threadfence + ACQ_REL agent atomic; FP add commutative -> bitwise
//   deterministic). Flags zeroed per launch. ws < 91MiB -> fallback: green
//   single-block path (if constexpr). Compute core byte-identical to R22.

#define SS 1280
#define DD 64
#define NH 16
#define TK 64
#define QB 128
#define NITEMS 960
#define SLOTF 8320                     // floats per partial slot: 128*64 + 128

typedef __attribute__((ext_vector_type(8))) short bf16x8;
typedef __attribute__((ext_vector_type(16))) float f32x16;

union UA { uint u[4]; bf16x8 v; };

__device__ inline uint pk2(float a, float b) {
    union { __hip_bfloat162 h; uint u; } cv;
    cv.h = __float22bfloat162_rn(float2{a, b});   // v_cvt_pk_bf16_f32
    return cv.u;
}

// volatile: convergent cross-lane op (R17/R18 lesson)
__device__ inline void pl32(uint& a, uint& b) {
    asm volatile("v_permlane32_swap_b32 %0, %1" : "+v"(a), "+v"(b));
}

#define WAITVM2() asm volatile("s_waitcnt vmcnt(2)" ::: "memory")

// longest-first static item order
__device__ inline void decode_item(int i, int& b, int& h, int& qt) {
    if (i < 96)  { qt = 9; b = i / 16; h = i % 16; return; }                   // N=20
    i -= 96;
    if (i < 256) { b = i / 128; qt = 1 + (i % 128) / 16; h = i % 16; return; } // t2i qt1-8, N=18
    i -= 256;
    if (i < 32)  { b = 2 + i / 16; qt = 8; h = i % 16; return; }               // lm qt8, N=18
    i -= 32;
    if (i < 32)  { b = 4 + i / 16; qt = 8; h = i % 16; return; }               // mmu qt8, N=18
    i -= 32;
    if (i < 256) { b = 4 + i / 128; qt = (i % 128) / 16; h = i % 16; return; } // mmu qt0-7, N=17
    i -= 256;
    if (i < 224) { qt = 7 - i / 32; b = 2 + (i % 32) / 16; h = i % 16; return; } // lm qt7..1
    i -= 224;
    if (i < 32)  { b = 2 + i / 16; qt = 0; h = i % 16; return; }               // lm qt0, N=2
    i -= 32;
    b = i / 16; qt = 0; h = i % 16;                                            // t2i qt0, N=2
}

__global__ void zflags_kernel(int* flags) {
    const int i = blockIdx.x * 256 + threadIdx.x;
    if (i < NITEMS) flags[i] = 0;
}

// ============ fused prepass: K->bf16 (gx<3840) | V->Vt[d][kv] bf16 (gx>=3840) ============
__global__ __launch_bounds__(256) void prepass8(
    const float* __restrict__ K, const float* __restrict__ V,
    ushort* __restrict__ Kb, ushort* __restrict__ Vtb)
{
    const int gx = blockIdx.x;
    const int t  = threadIdx.x;
    if (gx < 3840) {
        const size_t e = ((size_t)gx * 256 + t) * 8;
        const float4 a = *(const float4*)(K + e);
        const float4 c = *(const float4*)(K + e + 4);
        UA u;
        u.u[0] = pk2(a.x, a.y); u.u[1] = pk2(a.z, a.w);
        u.u[2] = pk2(c.x, c.y); u.u[3] = pk2(c.z, c.w);
        *(bf16x8*)(Kb + e) = u.v;
    } else {
        const int g   = gx - 3840;
        const int kvt = g % 20;
        const int p   = g / 20;
        __shared__ float T[64 * 67];
#pragma unroll
        for (int i = 0; i < 16; ++i) {
            const int idx = t + 256 * i;
            T[(idx >> 6) * 67 + (idx & 63)] = V[(size_t)p * (SS * DD) + (size_t)(kvt * 64) * DD + idx];
        }
        __syncthreads();
        ushort* dst = Vtb + (size_t)p * (DD * SS) + kvt * 64;
#pragma unroll
        for (int i = 0; i < 2; ++i) {
            const int c0 = t + 256 * i;
            const int d = c0 >> 3, kc = c0 & 7;
            UA u;
#pragma unroll
            for (int j = 0; j < 4; ++j)
                u.u[j] = pk2(T[(kc * 8 + 2 * j) * 67 + d], T[(kc * 8 + 2 * j + 1) * 67 + d]);
            *(bf16x8*)(dst + (size_t)d * SS + kc * 8) = u.v;
        }
    }
}

// ============================ main attention kernel ============================
template<bool SPLIT>
__global__ __launch_bounds__(256) void omni_attn23(
    const float* __restrict__ Q, const ushort* __restrict__ Kb,
    const ushort* __restrict__ Vtb, float* __restrict__ O,
    float* __restrict__ Pslots, int* __restrict__ flags)
{
    const int bid  = blockIdx.x;
    const int item = SPLIT ? (bid >> 1) : bid;
    const int half = SPLIT ? (bid & 1) : 0;
    int b, h, qt;
    decode_item(item, b, h, qt);           // longest-first dispatch order

    const int t   = threadIdx.x;
    const int w   = t >> 6;
    const int l   = t & 63;
    const int l31 = l & 31;
    const int hi2 = l >> 5;

    const int p   = b * NH + h;
    const int qb0 = qt * QB;
    const int qw0 = qb0 + w * 32;
    const int qr  = qw0 + l31;
    const size_t pbase = (size_t)p * (SS * DD);

    const int bt = (b < 2) ? 0 : (b < 4) ? 1 : 2;
    const int pe = (b == 0) ? 80 : (b == 1) ? 100 : 0;
    const int qmax_blk = qb0 + QB - 1;
    const int qmax_w   = qw0 + 31;
    const bool blk_img = (qb0 + QB - 1 >= 128) && (qb0 < 1152);
    const bool w_img   = (qw0 >= 128) && (qw0 < 1152);
    const bool qin     = (qr >= 128) && (qr < 1152);

    __shared__ char smem[3 * 8192];        // 3 K-only buffers
    __shared__ int s_old;

    const float scale = 0.125f * 1.44269504088896340736f;

    // per-thread K staging offsets (inverse-swizzled source)
    int koff[2];
#pragma unroll
    for (int rd = 0; rd < 2; ++rd) {
        const int ci  = rd * 256 + w * 64 + l;
        const int row = ci >> 3, cc = ci & 7;
        koff[rd] = row * DD + (cc ^ (row & 7)) * 8;
    }

    // ---- Q fragments, scale folded in ----
    bf16x8 qf[4];
#pragma unroll
    for (int ks = 0; ks < 4; ++ks) {
        const float* src = Q + pbase + (size_t)qr * DD + ks * 16 + hi2 * 8;
        const float4 a = *(const float4*)(src);
        const float4 c = *(const float4*)(src + 4);
        UA u;
        u.u[0] = pk2(a.x * scale, a.y * scale); u.u[1] = pk2(a.z * scale, a.w * scale);
        u.u[2] = pk2(c.x * scale, c.y * scale); u.u[3] = pk2(c.z * scale, c.w * scale);
        qf[ks] = u.v;
    }

    f32x16 o_acc[2];
#pragma unroll
    for (int ntd = 0; ntd < 2; ++ntd)
#pragma unroll
        for (int r = 0; r < 16; ++r) o_acc[ntd][r] = 0.f;
    float psum0 = 0.f, psum1 = 0.f;

    auto need_blk = [&](int k0) -> bool {
        if (bt == 0) return (k0 <= qmax_blk) || (blk_img && k0 >= 128 && k0 < 1152);
        if (bt == 1) return (k0 <= qmax_blk);
        return (k0 <= qmax_blk) || (k0 < 1027);
    };
    auto next_tile = [&](int k) -> int {
        k += TK;
        while (k < SS && !need_blk(k)) k += TK;
        return k;
    };
    auto advance = [&](int k) -> int {     // stride-2 over needed list when SPLIT
        k = next_tile(k);
        if (SPLIT && k < SS) k = next_tile(k);
        return k;
    };
    auto stageK = [&](int bsel, int k0s) {
        char* buf = smem + bsel * 8192;
        const ushort* Kp = Kb + pbase + (size_t)k0s * DD;
#pragma unroll
        for (int rd = 0; rd < 2; ++rd) {
            char* lb = buf + (rd * 256 + w * 64) * 16;
            __builtin_amdgcn_global_load_lds(
                (const __attribute__((address_space(1))) void*)(Kp + koff[rd]),
                (__attribute__((address_space(3))) void*)lb, 16, 0, 0);
        }
    };

    // V per-lane base rows
    const ushort* vrow0 = Vtb + pbase + (size_t)l31 * SS + hi2 * 8;
    const ushort* vrow1 = vrow0 + 32 * SS;

    // ---- 3-buffer, 2-deep pipeline (every item/half has >= 1 tile) ----
    int ka = 0, cur = 0;
    if (SPLIT && half == 1) ka = next_tile(0);   // >= 2 needed tiles per item
    int kb = advance(ka);
    int kc = (kb < SS) ? advance(kb) : SS;
    stageK(0, ka);
    stageK(1, (kb < SS) ? kb : 0);
    WAITVM2();                             // K(0) landed; K(1) in flight
    __builtin_amdgcn_s_barrier();
    __builtin_amdgcn_sched_barrier(0);

    while (true) {
        const int k0 = ka;
        const bool kv_img = (k0 >= 128) && (k0 < 1152);
        bool need_w, full_w;
        if (bt == 0) {
            need_w = (k0 <= qmax_w) || (w_img && kv_img);
            full_w = ((k0 >= pe) && (k0 + 63 <= qw0)) || (w_img && kv_img);
        } else if (bt == 1) {
            need_w = (k0 <= qmax_w);
            full_w = (k0 + 63 <= qw0);
        } else {
            need_w = (k0 <= qmax_w) || (k0 < 1027);
            full_w = (k0 + 63 <= qw0) || (k0 + 63 < 1027);
        }

        if (need_w) {
            char* cbuf = smem + cur * 8192;
#pragma unroll
            for (int nt = 0; nt < 2; ++nt) {
                const int vb = k0 + nt * 32;
                bf16x8 vfn[4];
                vfn[0] = *(const bf16x8*)(vrow0 + vb);
                vfn[1] = *(const bf16x8*)(vrow0 + vb + 16);
                vfn[2] = *(const bf16x8*)(vrow1 + vb);
                vfn[3] = *(const bf16x8*)(vrow1 + vb + 16);

                f32x16 s;
#pragma unroll
                for (int r = 0; r < 16; ++r) s[r] = 0.f;
                __builtin_amdgcn_s_setprio(1);
#pragma unroll
                for (int ksd = 0; ksd < 4; ++ksd) {
                    const int row = nt * 32 + l31;
                    int off = row * 128 + ksd * 32 + hi2 * 16;
                    off ^= (row & 7) << 4;
                    const bf16x8 kf = *(const bf16x8*)(cbuf + off);
                    s = __builtin_amdgcn_mfma_f32_32x32x16_bf16(kf, qf[ksd], s, 0, 0, 0);
                }
                __builtin_amdgcn_s_setprio(0);

                const int c0k = k0 + nt * 32;
                const bool kvi = (c0k >= 128) && (c0k < 1152);
                uint c[8];
#pragma unroll
                for (int i = 0; i < 8; ++i) {
                    float pa, pb;
                    if (full_w) {
                        pa = __builtin_amdgcn_exp2f(s[2 * i]);
                        pb = __builtin_amdgcn_exp2f(s[2 * i + 1]);
                    } else {
                        const int r0i = 2 * i, r1i = 2 * i + 1;
                        const int kva = c0k + (r0i & 3) + 8 * (r0i >> 2) + 4 * hi2;
                        const int kvb = c0k + (r1i & 3) + 8 * (r1i >> 2) + 4 * hi2;
                        bool aa, ab;
                        if (bt == 0) {
                            aa = (qr == kva) | ((kva >= pe) & (qr >= kva)) | (qin & kvi);
                            ab = (qr == kvb) | ((kvb >= pe) & (qr >= kvb)) | (qin & kvi);
                        } else if (bt == 1) {
                            aa = (qr >= kva); ab = (qr >= kvb);
                        } else {
                            aa = (qr >= kva) | (kva < 1027);
                            ab = (qr >= kvb) | (kvb < 1027);
                        }
                        pa = aa ? __builtin_amdgcn_exp2f(s[2 * i]) : 0.f;
                        pb = ab ? __builtin_amdgcn_exp2f(s[2 * i + 1]) : 0.f;
                    }
                    if (i & 1) psum1 += pa + pb; else psum0 += pa + pb;
                    c[i] = pk2(pa, pb);
                }

                UA A0, A1;
                {
                    uint a0 = c[0], b0 = c[2]; pl32(a0, b0);
                    uint a1 = c[1], b1 = c[3]; pl32(a1, b1);
                    A0.u[0] = a0; A0.u[1] = a1; A0.u[2] = b0; A0.u[3] = b1;
                    uint a2 = c[4], b2 = c[6]; pl32(a2, b2);
                    uint a3 = c[5], b3 = c[7]; pl32(a3, b3);
                    A1.u[0] = a2; A1.u[1] = a3; A1.u[2] = b2; A1.u[3] = b3;
                }

                __builtin_amdgcn_s_setprio(1);
                o_acc[0] = __builtin_amdgcn_mfma_f32_32x32x16_bf16(A0.v, vfn[0], o_acc[0], 0, 0, 0);
                o_acc[0] = __builtin_amdgcn_mfma_f32_32x32x16_bf16(A1.v, vfn[1], o_acc[0], 0, 0, 0);
                o_acc[1] = __builtin_amdgcn_mfma_f32_32x32x16_bf16(A0.v, vfn[2], o_acc[1], 0, 0, 0);
                o_acc[1] = __builtin_amdgcn_mfma_f32_32x32x16_bf16(A1.v, vfn[3], o_acc[1], 0, 0, 0);
                __builtin_amdgcn_s_setprio(0);
            }
        }

        stageK((cur + 2) % 3, (kc < SS) ? kc : 0);
        WAITVM2();
        __builtin_amdgcn_s_barrier();
        __builtin_amdgcn_sched_barrier(0);
        if (kb >= SS) break;
        ka = kb; kb = kc; kc = (kc < SS) ? advance(kc) : SS;
        cur = (cur + 1) % 3;
    }

    // ---- own-half row sums: lane l holds total for q = qw0 + l31 ----
    float psum = psum0 + psum1;
    psum += __shfl_xor(psum, 32, 64);

    if constexpr (!SPLIT) {
#pragma unroll
        for (int r = 0; r < 16; ++r) {
            const int q_loc = (r & 3) + 8 * (r >> 2) + 4 * hi2;
            const float tv = __shfl(psum, q_loc, 64);
            const float iv = 1.f / tv;
            float* dst = O + pbase + (size_t)(qw0 + q_loc) * DD + l31;
            dst[0]  = o_acc[0][r] * iv;
            dst[32] = o_acc[1][r] * iv;
        }
        return;
    } else {
        // ---- write my partial slot ----
        float* slot = Pslots + ((size_t)item * 2 + half) * SLOTF;
#pragma unroll
        for (int r = 0; r < 16; ++r) {
            const int q_loc = (r & 3) + 8 * (r >> 2) + 4 * hi2;
            float* dst = slot + (w * 32 + q_loc) * 64 + l31;
            dst[0]  = o_acc[0][r];
            dst[32] = o_acc[1][r];
        }
        if (l < 32) slot[8192 + w * 32 + l31] = psum;

        __threadfence();                  // release my stores (agent scope)
        __syncthreads();                  // all waves' stores done
        if (t == 0)
            s_old = __hip_atomic_fetch_add(flags + item, 1,
                                           __ATOMIC_ACQ_REL, __HIP_MEMORY_SCOPE_AGENT);
        __syncthreads();
        if (s_old == 0) return;           // first finisher: partner will merge

        // ---- last finisher: merge partner partial (in registers) ----
        __threadfence();                  // acquire partner's stores
        const float* ps = Pslots + ((size_t)item * 2 + (half ^ 1)) * SLOTF;
        float ptot = psum + ps[8192 + w * 32 + l31];   // q = qw0 + l31
#pragma unroll
        for (int r = 0; r < 16; ++r) {
            const int q_loc = (r & 3) + 8 * (r >> 2) + 4 * hi2;
            const int row = w * 32 + q_loc;
            const float tv = __shfl(ptot, q_loc, 64);
            const float iv = 1.f / tv;
            float* dst = O + pbase + (size_t)(qw0 + q_loc) * DD + l31;
            dst[0]  = (o_acc[0][r] + ps[row * 64 + l31])      * iv;
            dst[32] = (o_acc[1][r] + ps[row * 64 + 32 + l31]) * iv;
        }
    }
}

extern "C" void kernel_launch(void* const* d_in, const int* in_sizes, int n_in,
                              void* d_out, int out_size, void* d_ws, size_t ws_size,
                              hipStream_t stream) {
    const float* q = (const float*)d_in[0];
    const float* k = (const float*)d_in[1];
    const float* v = (const float*)d_in[2];
    float* o = (float*)d_out;

    const size_t NE = 7864320ULL;          // B*H*S*D
    ushort* Kb  = (ushort*)d_ws;
    ushort* Vtb = Kb + NE;
    char* base  = (char*)d_ws + 2 * NE * sizeof(ushort);   // 31.46 MB
    int*   flags  = (int*)base;
    float* Pslots = (float*)(base + 4096);                 // flags padded to 4KB
    const size_t need = 2 * NE * sizeof(ushort) + 4096 +
                        (size_t)2 * NITEMS * SLOTF * sizeof(float);  // ~95.4 MB

    prepass8<<<dim3(5760), 256, 0, stream>>>(k, v, Kb, Vtb);
    if (ws_size >= need) {
        zflags_kernel<<<dim3((NITEMS + 255) / 256), 256, 0, stream>>>(flags);
        omni_attn23<true><<<dim3(2 * NITEMS), 256, 0, stream>>>(q, Kb, Vtb, o, Pslots, flags);
    } else {
        omni_attn23<false><<<dim3(NITEMS), 256, 0, stream>>>(q, Kb, Vtb, o, nullptr, nullptr);
    }
}

// Round 24
// 127.555 us; speedup vs baseline: 4.5250x; 4.5250x over previous
//
#include <hip/hip_runtime.h>
#include <hip/hip_bf16.h>
#include <math.h>

// OmniAttentionMechanism: flex-attention, mixed t2i/lm/mmu mask.
// B=6 (b0,b1: t2i pe=80/100; b2,b3: lm; b4,b5: mmu kv<1027), H=16, S=1280, D=64. fp32 I/O.
//
// Round 24: KV-SPLIT x2, FENCE-FREE (3-kernel pipeline).
//   R23's 6x regression: per-block agent-scope fences/atomics on non-coherent
//   per-XCD L2s force L2 writeback+invalidate 2x/block -> serialized cache
//   maintenance + K/V refetch (FETCH 2x). Lesson: cross-block handoff belongs
//   at KERNEL BOUNDARIES on CDNA4.
//   Fix: split kernel always writes partial slots with plain stores (no sync);
//   separate merge kernel (960 blocks, memory-bound ~20us) adds partials,
//   normalizes, writes O. Compute core byte-identical to R22/R23.

#define SS 1280
#define DD 64
#define NH 16
#define TK 64
#define QB 128
#define NITEMS 960
#define SLOTF 8320                     // floats per partial slot: 128*64 + 128

typedef __attribute__((ext_vector_type(8))) short bf16x8;
typedef __attribute__((ext_vector_type(16))) float f32x16;

union UA { uint u[4]; bf16x8 v; };

__device__ inline uint pk2(float a, float b) {
    union { __hip_bfloat162 h; uint u; } cv;
    cv.h = __float22bfloat162_rn(float2{a, b});   // v_cvt_pk_bf16_f32
    return cv.u;
}

// volatile: convergent cross-lane op (R17/R18 lesson)
__device__ inline void pl32(uint& a, uint& b) {
    asm volatile("v_permlane32_swap_b32 %0, %1" : "+v"(a), "+v"(b));
}

#define WAITVM2() asm volatile("s_waitcnt vmcnt(2)" ::: "memory")

// longest-first static item order
__device__ inline void decode_item(int i, int& b, int& h, int& qt) {
    if (i < 96)  { qt = 9; b = i / 16; h = i % 16; return; }                   // N=20
    i -= 96;
    if (i < 256) { b = i / 128; qt = 1 + (i % 128) / 16; h = i % 16; return; } // t2i qt1-8, N=18
    i -= 256;
    if (i < 32)  { b = 2 + i / 16; qt = 8; h = i % 16; return; }               // lm qt8, N=18
    i -= 32;
    if (i < 32)  { b = 4 + i / 16; qt = 8; h = i % 16; return; }               // mmu qt8, N=18
    i -= 32;
    if (i < 256) { b = 4 + i / 128; qt = (i % 128) / 16; h = i % 16; return; } // mmu qt0-7, N=17
    i -= 256;
    if (i < 224) { qt = 7 - i / 32; b = 2 + (i % 32) / 16; h = i % 16; return; } // lm qt7..1
    i -= 224;
    if (i < 32)  { b = 2 + i / 16; qt = 0; h = i % 16; return; }               // lm qt0, N=2
    i -= 32;
    b = i / 16; qt = 0; h = i % 16;                                            // t2i qt0, N=2
}

// ============ fused prepass: K->bf16 (gx<3840) | V->Vt[d][kv] bf16 (gx>=3840) ============
__global__ __launch_bounds__(256) void prepass8(
    const float* __restrict__ K, const float* __restrict__ V,
    ushort* __restrict__ Kb, ushort* __restrict__ Vtb)
{
    const int gx = blockIdx.x;
    const int t  = threadIdx.x;
    if (gx < 3840) {
        const size_t e = ((size_t)gx * 256 + t) * 8;
        const float4 a = *(const float4*)(K + e);
        const float4 c = *(const float4*)(K + e + 4);
        UA u;
        u.u[0] = pk2(a.x, a.y); u.u[1] = pk2(a.z, a.w);
        u.u[2] = pk2(c.x, c.y); u.u[3] = pk2(c.z, c.w);
        *(bf16x8*)(Kb + e) = u.v;
    } else {
        const int g   = gx - 3840;
        const int kvt = g % 20;
        const int p   = g / 20;
        __shared__ float T[64 * 67];
#pragma unroll
        for (int i = 0; i < 16; ++i) {
            const int idx = t + 256 * i;
            T[(idx >> 6) * 67 + (idx & 63)] = V[(size_t)p * (SS * DD) + (size_t)(kvt * 64) * DD + idx];
        }
        __syncthreads();
        ushort* dst = Vtb + (size_t)p * (DD * SS) + kvt * 64;
#pragma unroll
        for (int i = 0; i < 2; ++i) {
            const int c0 = t + 256 * i;
            const int d = c0 >> 3, kc = c0 & 7;
            UA u;
#pragma unroll
            for (int j = 0; j < 4; ++j)
                u.u[j] = pk2(T[(kc * 8 + 2 * j) * 67 + d], T[(kc * 8 + 2 * j + 1) * 67 + d]);
            *(bf16x8*)(dst + (size_t)d * SS + kc * 8) = u.v;
        }
    }
}

// ============================ split attention kernel ============================
template<bool SPLIT>
__global__ __launch_bounds__(256) void omni_split24(
    const float* __restrict__ Q, const ushort* __restrict__ Kb,
    const ushort* __restrict__ Vtb, float* __restrict__ O,
    float* __restrict__ Pslots)
{
    const int bid  = blockIdx.x;
    const int item = SPLIT ? (bid >> 1) : bid;
    const int half = SPLIT ? (bid & 1) : 0;
    int b, h, qt;
    decode_item(item, b, h, qt);           // longest-first dispatch order

    const int t   = threadIdx.x;
    const int w   = t >> 6;
    const int l   = t & 63;
    const int l31 = l & 31;
    const int hi2 = l >> 5;

    const int p   = b * NH + h;
    const int qb0 = qt * QB;
    const int qw0 = qb0 + w * 32;
    const int qr  = qw0 + l31;
    const size_t pbase = (size_t)p * (SS * DD);

    const int bt = (b < 2) ? 0 : (b < 4) ? 1 : 2;
    const int pe = (b == 0) ? 80 : (b == 1) ? 100 : 0;
    const int qmax_blk = qb0 + QB - 1;
    const int qmax_w   = qw0 + 31;
    const bool blk_img = (qb0 + QB - 1 >= 128) && (qb0 < 1152);
    const bool w_img   = (qw0 >= 128) && (qw0 < 1152);
    const bool qin     = (qr >= 128) && (qr < 1152);

    __shared__ char smem[3 * 8192];        // 3 K-only buffers

    const float scale = 0.125f * 1.44269504088896340736f;

    int koff[2];
#pragma unroll
    for (int rd = 0; rd < 2; ++rd) {
        const int ci  = rd * 256 + w * 64 + l;
        const int row = ci >> 3, cc = ci & 7;
        koff[rd] = row * DD + (cc ^ (row & 7)) * 8;
    }

    // ---- Q fragments, scale folded in ----
    bf16x8 qf[4];
#pragma unroll
    for (int ks = 0; ks < 4; ++ks) {
        const float* src = Q + pbase + (size_t)qr * DD + ks * 16 + hi2 * 8;
        const float4 a = *(const float4*)(src);
        const float4 c = *(const float4*)(src + 4);
        UA u;
        u.u[0] = pk2(a.x * scale, a.y * scale); u.u[1] = pk2(a.z * scale, a.w * scale);
        u.u[2] = pk2(c.x * scale, c.y * scale); u.u[3] = pk2(c.z * scale, c.w * scale);
        qf[ks] = u.v;
    }

    f32x16 o_acc[2];
#pragma unroll
    for (int ntd = 0; ntd < 2; ++ntd)
#pragma unroll
        for (int r = 0; r < 16; ++r) o_acc[ntd][r] = 0.f;
    float psum0 = 0.f, psum1 = 0.f;

    auto need_blk = [&](int k0) -> bool {
        if (bt == 0) return (k0 <= qmax_blk) || (blk_img && k0 >= 128 && k0 < 1152);
        if (bt == 1) return (k0 <= qmax_blk);
        return (k0 <= qmax_blk) || (k0 < 1027);
    };
    auto next_tile = [&](int k) -> int {
        k += TK;
        while (k < SS && !need_blk(k)) k += TK;
        return k;
    };
    auto advance = [&](int k) -> int {     // stride-2 over needed list when SPLIT
        k = next_tile(k);
        if (SPLIT && k < SS) k = next_tile(k);
        return k;
    };
    auto stageK = [&](int bsel, int k0s) {
        char* buf = smem + bsel * 8192;
        const ushort* Kp = Kb + pbase + (size_t)k0s * DD;
#pragma unroll
        for (int rd = 0; rd < 2; ++rd) {
            char* lb = buf + (rd * 256 + w * 64) * 16;
            __builtin_amdgcn_global_load_lds(
                (const __attribute__((address_space(1))) void*)(Kp + koff[rd]),
                (__attribute__((address_space(3))) void*)lb, 16, 0, 0);
        }
    };

    const ushort* vrow0 = Vtb + pbase + (size_t)l31 * SS + hi2 * 8;
    const ushort* vrow1 = vrow0 + 32 * SS;

    // ---- 3-buffer, 2-deep pipeline (each item has >=2 needed tiles -> each half >=1) ----
    int ka = 0, cur = 0;
    if (SPLIT && half == 1) ka = next_tile(0);
    int kb = advance(ka);
    int kc = (kb < SS) ? advance(kb) : SS;
    stageK(0, ka);
    stageK(1, (kb < SS) ? kb : 0);
    WAITVM2();
    __builtin_amdgcn_s_barrier();
    __builtin_amdgcn_sched_barrier(0);

    while (true) {
        const int k0 = ka;
        const bool kv_img = (k0 >= 128) && (k0 < 1152);
        bool need_w, full_w;
        if (bt == 0) {
            need_w = (k0 <= qmax_w) || (w_img && kv_img);
            full_w = ((k0 >= pe) && (k0 + 63 <= qw0)) || (w_img && kv_img);
        } else if (bt == 1) {
            need_w = (k0 <= qmax_w);
            full_w = (k0 + 63 <= qw0);
        } else {
            need_w = (k0 <= qmax_w) || (k0 < 1027);
            full_w = (k0 + 63 <= qw0) || (k0 + 63 < 1027);
        }

        if (need_w) {
            char* cbuf = smem + cur * 8192;
#pragma unroll
            for (int nt = 0; nt < 2; ++nt) {
                const int vb = k0 + nt * 32;
                bf16x8 vfn[4];
                vfn[0] = *(const bf16x8*)(vrow0 + vb);
                vfn[1] = *(const bf16x8*)(vrow0 + vb + 16);
                vfn[2] = *(const bf16x8*)(vrow1 + vb);
                vfn[3] = *(const bf16x8*)(vrow1 + vb + 16);

                f32x16 s;
#pragma unroll
                for (int r = 0; r < 16; ++r) s[r] = 0.f;
                __builtin_amdgcn_s_setprio(1);
#pragma unroll
                for (int ksd = 0; ksd < 4; ++ksd) {
                    const int row = nt * 32 + l31;
                    int off = row * 128 + ksd * 32 + hi2 * 16;
                    off ^= (row & 7) << 4;
                    const bf16x8 kf = *(const bf16x8*)(cbuf + off);
                    s = __builtin_amdgcn_mfma_f32_32x32x16_bf16(kf, qf[ksd], s, 0, 0, 0);
                }
                __builtin_amdgcn_s_setprio(0);

                const int c0k = k0 + nt * 32;
                const bool kvi = (c0k >= 128) && (c0k < 1152);
                uint c[8];
#pragma unroll
                for (int i = 0; i < 8; ++i) {
                    float pa, pb;
                    if (full_w) {
                        pa = __builtin_amdgcn_exp2f(s[2 * i]);
                        pb = __builtin_amdgcn_exp2f(s[2 * i + 1]);
                    } else {
                        const int r0i = 2 * i, r1i = 2 * i + 1;
                        const int kva = c0k + (r0i & 3) + 8 * (r0i >> 2) + 4 * hi2;
                        const int kvb = c0k + (r1i & 3) + 8 * (r1i >> 2) + 4 * hi2;
                        bool aa, ab;
                        if (bt == 0) {
                            aa = (qr == kva) | ((kva >= pe) & (qr >= kva)) | (qin & kvi);
                            ab = (qr == kvb) | ((kvb >= pe) & (qr >= kvb)) | (qin & kvi);
                        } else if (bt == 1) {
                            aa = (qr >= kva); ab = (qr >= kvb);
                        } else {
                            aa = (qr >= kva) | (kva < 1027);
                            ab = (qr >= kvb) | (kvb < 1027);
                        }
                        pa = aa ? __builtin_amdgcn_exp2f(s[2 * i]) : 0.f;
                        pb = ab ? __builtin_amdgcn_exp2f(s[2 * i + 1]) : 0.f;
                    }
                    if (i & 1) psum1 += pa + pb; else psum0 += pa + pb;
                    c[i] = pk2(pa, pb);
                }

                UA A0, A1;
                {
                    uint a0 = c[0], b0 = c[2]; pl32(a0, b0);
                    uint a1 = c[1], b1 = c[3]; pl32(a1, b1);
                    A0.u[0] = a0; A0.u[1] = a1; A0.u[2] = b0; A0.u[3] = b1;
                    uint a2 = c[4], b2 = c[6]; pl32(a2, b2);
                    uint a3 = c[5], b3 = c[7]; pl32(a3, b3);
                    A1.u[0] = a2; A1.u[1] = a3; A1.u[2] = b2; A1.u[3] = b3;
                }

                __builtin_amdgcn_s_setprio(1);
                o_acc[0] = __builtin_amdgcn_mfma_f32_32x32x16_bf16(A0.v, vfn[0], o_acc[0], 0, 0, 0);
                o_acc[0] = __builtin_amdgcn_mfma_f32_32x32x16_bf16(A1.v, vfn[1], o_acc[0], 0, 0, 0);
                o_acc[1] = __builtin_amdgcn_mfma_f32_32x32x16_bf16(A0.v, vfn[2], o_acc[1], 0, 0, 0);
                o_acc[1] = __builtin_amdgcn_mfma_f32_32x32x16_bf16(A1.v, vfn[3], o_acc[1], 0, 0, 0);
                __builtin_amdgcn_s_setprio(0);
            }
        }

        stageK((cur + 2) % 3, (kc < SS) ? kc : 0);
        WAITVM2();
        __builtin_amdgcn_s_barrier();
        __builtin_amdgcn_sched_barrier(0);
        if (kb >= SS) break;
        ka = kb; kb = kc; kc = (kc < SS) ? advance(kc) : SS;
        cur = (cur + 1) % 3;
    }

    float psum = psum0 + psum1;
    psum += __shfl_xor(psum, 32, 64);      // lane l: own-half total for q = qw0+l31

    if constexpr (!SPLIT) {
#pragma unroll
        for (int r = 0; r < 16; ++r) {
            const int q_loc = (r & 3) + 8 * (r >> 2) + 4 * hi2;
            const float tv = __shfl(psum, q_loc, 64);
            const float iv = 1.f / tv;
            float* dst = O + pbase + (size_t)(qw0 + q_loc) * DD + l31;
            dst[0]  = o_acc[0][r] * iv;
            dst[32] = o_acc[1][r] * iv;
        }
    } else {
        // ---- plain stores of partial; coherence comes from the kernel boundary ----
        float* slot = Pslots + ((size_t)item * 2 + half) * SLOTF;
#pragma unroll
        for (int r = 0; r < 16; ++r) {
            const int q_loc = (r & 3) + 8 * (r >> 2) + 4 * hi2;
            float* dst = slot + (w * 32 + q_loc) * 64 + l31;
            dst[0]  = o_acc[0][r];
            dst[32] = o_acc[1][r];
        }
        if (l < 32) slot[8192 + w * 32 + l31] = psum;
    }
}

// ============================ merge kernel (memory-bound) ============================
__global__ __launch_bounds__(256) void merge24(
    const float* __restrict__ Pslots, float* __restrict__ O)
{
    const int item = blockIdx.x;
    const int t    = threadIdx.x;
    int b, h, qt;
    decode_item(item, b, h, qt);
    const size_t pbase = (size_t)(b * NH + h) * (SS * DD);
    const float* s0 = Pslots + (size_t)item * 2 * SLOTF;
    const float* s1 = s0 + SLOTF;

    const int row = t >> 1;                // 0..127
    const int c0  = (t & 1) * 32;          // column half
    const float inv = 1.f / (s0[8192 + row] + s1[8192 + row]);
    float* dst = O + pbase + (size_t)(qt * QB + row) * DD + c0;
    const float* a = s0 + row * 64 + c0;
    const float* bb = s1 + row * 64 + c0;
#pragma unroll
    for (int j = 0; j < 8; ++j) {
        const float4 x = *(const float4*)(a + j * 4);
        const float4 y = *(const float4*)(bb + j * 4);
        *(float4*)(dst + j * 4) = make_float4((x.x + y.x) * inv, (x.y + y.y) * inv,
                                              (x.z + y.z) * inv, (x.w + y.w) * inv);
    }
}

extern "C" void kernel_launch(void* const* d_in, const int* in_sizes, int n_in,
                              void* d_out, int out_size, void* d_ws, size_t ws_size,
                              hipStream_t stream) {
    const float* q = (const float*)d_in[0];
    const float* k = (const float*)d_in[1];
    const float* v = (const float*)d_in[2];
    float* o = (float*)d_out;

    const size_t NE = 7864320ULL;          // B*H*S*D
    ushort* Kb  = (ushort*)d_ws;
    ushort* Vtb = Kb + NE;
    float* Pslots = (float*)((char*)d_ws + 2 * NE * sizeof(ushort));
    const size_t need = 2 * NE * sizeof(ushort) +
                        (size_t)2 * NITEMS * SLOTF * sizeof(float);  // ~95.4 MB

    prepass8<<<dim3(5760), 256, 0, stream>>>(k, v, Kb, Vtb);
    if (ws_size >= need) {
        omni_split24<true><<<dim3(2 * NITEMS), 256, 0, stream>>>(q, Kb, Vtb, o, Pslots);
        merge24<<<dim3(NITEMS), 256, 0, stream>>>(Pslots, o);
    } else {
        omni_split24<false><<<dim3(NITEMS), 256, 0, stream>>>(q, Kb, Vtb, o, nullptr);
    }
}

// Round 25
// 120.370 us; speedup vs baseline: 4.7950x; 1.0597x over previous
//
#include <hip/hip_runtime.h>
#include <hip/hip_bf16.h>
#include <math.h>

// OmniAttentionMechanism: flex-attention, mixed t2i/lm/mmu mask.
// B=6 (b0,b1: t2i pe=80/100; b2,b3: lm; b4,b5: mmu kv<1027), H=16, S=1280, D=64. fp32 I/O.
//
// Round 25 (on R22 green, 99.7us total): BODY-SIZE experiment (I-fetch theory).
//   R24's null (split @2x blocks/half chains = same 94.7us; all pipes <40%)
//   leaves one work-proportional, occupancy-insensitive resource: L1I fetch of
//   the huge unrolled loop body. Change: merge full/partial paths into ONE
//   exp2 block — masks always computed (verified exprs), OR'd with full_w,
//   masked scores -> -inf -> exp2()=0. Body ~halves; +VALU on full tiles.
//   Discriminator: faster => I-fetch-bound confirmed; flat/slower => plateau.
//   Everything else byte-identical to R19/R22 (setprio fences, sync, ledger).

#define SS 1280
#define DD 64
#define NH 16
#define TK 64
#define QB 128
#define NITEMS 960

typedef __attribute__((ext_vector_type(8))) short bf16x8;
typedef __attribute__((ext_vector_type(16))) float f32x16;

union UA { uint u[4]; bf16x8 v; };

__device__ inline uint pk2(float a, float b) {
    union { __hip_bfloat162 h; uint u; } cv;
    cv.h = __float22bfloat162_rn(float2{a, b});   // v_cvt_pk_bf16_f32
    return cv.u;
}

// volatile: convergent cross-lane op (R17/R18 lesson)
__device__ inline void pl32(uint& a, uint& b) {
    asm volatile("v_permlane32_swap_b32 %0, %1" : "+v"(a), "+v"(b));
}

#define WAITVM2() asm volatile("s_waitcnt vmcnt(2)" ::: "memory")

// longest-first static item order
__device__ inline void decode_item(int i, int& b, int& h, int& qt) {
    if (i < 96)  { qt = 9; b = i / 16; h = i % 16; return; }                   // N=20
    i -= 96;
    if (i < 256) { b = i / 128; qt = 1 + (i % 128) / 16; h = i % 16; return; } // t2i qt1-8, N=18
    i -= 256;
    if (i < 32)  { b = 2 + i / 16; qt = 8; h = i % 16; return; }               // lm qt8, N=18
    i -= 32;
    if (i < 32)  { b = 4 + i / 16; qt = 8; h = i % 16; return; }               // mmu qt8, N=18
    i -= 32;
    if (i < 256) { b = 4 + i / 128; qt = (i % 128) / 16; h = i % 16; return; } // mmu qt0-7, N=17
    i -= 256;
    if (i < 224) { qt = 7 - i / 32; b = 2 + (i % 32) / 16; h = i % 16; return; } // lm qt7..1
    i -= 224;
    if (i < 32)  { b = 2 + i / 16; qt = 0; h = i % 16; return; }               // lm qt0, N=2
    i -= 32;
    b = i / 16; qt = 0; h = i % 16;                                            // t2i qt0, N=2
}

// ============ fused prepass: K->bf16 (gx<3840) | V->Vt[d][kv] bf16 (gx>=3840) ============
__global__ __launch_bounds__(256) void prepass8(
    const float* __restrict__ K, const float* __restrict__ V,
    ushort* __restrict__ Kb, ushort* __restrict__ Vtb)
{
    const int gx = blockIdx.x;
    const int t  = threadIdx.x;
    if (gx < 3840) {
        const size_t e = ((size_t)gx * 256 + t) * 8;
        const float4 a = *(const float4*)(K + e);
        const float4 c = *(const float4*)(K + e + 4);
        UA u;
        u.u[0] = pk2(a.x, a.y); u.u[1] = pk2(a.z, a.w);
        u.u[2] = pk2(c.x, c.y); u.u[3] = pk2(c.z, c.w);
        *(bf16x8*)(Kb + e) = u.v;
    } else {
        const int g   = gx - 3840;
        const int kvt = g % 20;
        const int p   = g / 20;
        __shared__ float T[64 * 67];
#pragma unroll
        for (int i = 0; i < 16; ++i) {
            const int idx = t + 256 * i;
            T[(idx >> 6) * 67 + (idx & 63)] = V[(size_t)p * (SS * DD) + (size_t)(kvt * 64) * DD + idx];
        }
        __syncthreads();
        ushort* dst = Vtb + (size_t)p * (DD * SS) + kvt * 64;
#pragma unroll
        for (int i = 0; i < 2; ++i) {
            const int c0 = t + 256 * i;
            const int d = c0 >> 3, kc = c0 & 7;
            UA u;
#pragma unroll
            for (int j = 0; j < 4; ++j)
                u.u[j] = pk2(T[(kc * 8 + 2 * j) * 67 + d], T[(kc * 8 + 2 * j + 1) * 67 + d]);
            *(bf16x8*)(dst + (size_t)d * SS + kc * 8) = u.v;
        }
    }
}

// ============================ main attention kernel ============================
__global__ __launch_bounds__(256) void omni_attn25(
    const float* __restrict__ Q, const ushort* __restrict__ Kb,
    const ushort* __restrict__ Vtb, float* __restrict__ O)
{
    int b, h, qt;
    decode_item(blockIdx.x, b, h, qt);     // longest-first dispatch order

    const int t   = threadIdx.x;
    const int w   = t >> 6;
    const int l   = t & 63;
    const int l31 = l & 31;
    const int hi2 = l >> 5;

    const int p   = b * NH + h;
    const int qb0 = qt * QB;
    const int qw0 = qb0 + w * 32;
    const int qr  = qw0 + l31;
    const size_t pbase = (size_t)p * (SS * DD);

    const int bt = (b < 2) ? 0 : (b < 4) ? 1 : 2;
    const int pe = (b == 0) ? 80 : (b == 1) ? 100 : 0;
    const int qmax_blk = qb0 + QB - 1;
    const int qmax_w   = qw0 + 31;
    const bool blk_img = (qb0 + QB - 1 >= 128) && (qb0 < 1152);
    const bool w_img   = (qw0 >= 128) && (qw0 < 1152);
    const bool qin     = (qr >= 128) && (qr < 1152);   // hoisted per-lane image test

    __shared__ char smem[3 * 8192];        // 3 K-only buffers

    const float scale = 0.125f * 1.44269504088896340736f;

    // per-thread K staging offsets (inverse-swizzled source)
    int koff[2];
#pragma unroll
    for (int rd = 0; rd < 2; ++rd) {
        const int ci  = rd * 256 + w * 64 + l;
        const int row = ci >> 3, cc = ci & 7;
        koff[rd] = row * DD + (cc ^ (row & 7)) * 8;
    }

    // ---- Q fragments, scale folded in (p = exp2(K·(Q*scale))) ----
    bf16x8 qf[4];
#pragma unroll
    for (int ks = 0; ks < 4; ++ks) {
        const float* src = Q + pbase + (size_t)qr * DD + ks * 16 + hi2 * 8;
        const float4 a = *(const float4*)(src);
        const float4 c = *(const float4*)(src + 4);
        UA u;
        u.u[0] = pk2(a.x * scale, a.y * scale); u.u[1] = pk2(a.z * scale, a.w * scale);
        u.u[2] = pk2(c.x * scale, c.y * scale); u.u[3] = pk2(c.z * scale, c.w * scale);
        qf[ks] = u.v;
    }

    f32x16 o_acc[2];
#pragma unroll
    for (int ntd = 0; ntd < 2; ++ntd)
#pragma unroll
        for (int r = 0; r < 16; ++r) o_acc[ntd][r] = 0.f;
    float psum0 = 0.f, psum1 = 0.f;

    auto need_blk = [&](int k0) -> bool {
        if (bt == 0) return (k0 <= qmax_blk) || (blk_img && k0 >= 128 && k0 < 1152);
        if (bt == 1) return (k0 <= qmax_blk);
        return (k0 <= qmax_blk) || (k0 < 1027);
    };
    auto next_tile = [&](int k) -> int {
        k += TK;
        while (k < SS && !need_blk(k)) k += TK;
        return k;
    };
    auto stageK = [&](int bsel, int k0s) {
        char* buf = smem + bsel * 8192;
        const ushort* Kp = Kb + pbase + (size_t)k0s * DD;
#pragma unroll
        for (int rd = 0; rd < 2; ++rd) {
            char* lb = buf + (rd * 256 + w * 64) * 16;
            __builtin_amdgcn_global_load_lds(
                (const __attribute__((address_space(1))) void*)(Kp + koff[rd]),
                (__attribute__((address_space(3))) void*)lb, 16, 0, 0);
        }
    };

    // V per-lane base rows (d = l31 and d = 32+l31), col offset hi2*8
    const ushort* vrow0 = Vtb + pbase + (size_t)l31 * SS + hi2 * 8;
    const ushort* vrow1 = vrow0 + 32 * SS;

    // ---- 3-buffer, 2-deep pipeline; stage issued post-compute; vmcnt(2)/tile ----
    int ka = 0, cur = 0;
    int kb = next_tile(0);                 // >= 2 tiles always exist
    int kc = (kb < SS) ? next_tile(kb) : SS;
    stageK(0, ka);
    stageK(1, kb);
    WAITVM2();                             // K(0) landed; K(1) in flight
    __builtin_amdgcn_s_barrier();
    __builtin_amdgcn_sched_barrier(0);

    while (true) {
        const int k0 = ka;
        const bool kv_img = (k0 >= 128) && (k0 < 1152);
        bool need_w, full_w;
        if (bt == 0) {
            need_w = (k0 <= qmax_w) || (w_img && kv_img);
            full_w = ((k0 >= pe) && (k0 + 63 <= qw0)) || (w_img && kv_img);
        } else if (bt == 1) {
            need_w = (k0 <= qmax_w);
            full_w = (k0 + 63 <= qw0);
        } else {
            need_w = (k0 <= qmax_w) || (k0 < 1027);
            full_w = (k0 + 63 <= qw0) || (k0 + 63 < 1027);
        }

        if (need_w) {
            char* cbuf = smem + cur * 8192;
#pragma unroll
            for (int nt = 0; nt < 2; ++nt) {
                // ---- V fragments for this kv half: 4 x bf16x8 (16 regs) ----
                const int vb = k0 + nt * 32;
                bf16x8 vfn[4];
                vfn[0] = *(const bf16x8*)(vrow0 + vb);
                vfn[1] = *(const bf16x8*)(vrow0 + vb + 16);
                vfn[2] = *(const bf16x8*)(vrow1 + vb);
                vfn[3] = *(const bf16x8*)(vrow1 + vb + 16);

                // ---- QK^T swapped: S[kv][q], A = K rows (LDS), B = Q cols ----
                f32x16 s;
#pragma unroll
                for (int r = 0; r < 16; ++r) s[r] = 0.f;
                __builtin_amdgcn_s_setprio(1);
#pragma unroll
                for (int ksd = 0; ksd < 4; ++ksd) {
                    const int row = nt * 32 + l31;
                    int off = row * 128 + ksd * 32 + hi2 * 16;
                    off ^= (row & 7) << 4;
                    const bf16x8 kf = *(const bf16x8*)(cbuf + off);
                    s = __builtin_amdgcn_mfma_f32_32x32x16_bf16(kf, qf[ksd], s, 0, 0, 0);
                }
                __builtin_amdgcn_s_setprio(0);

                // ---- UNIFIED mask + exp2 (single body; exp2(-inf)=0 masks) ----
                const int c0k = k0 + nt * 32;
                const bool kvi = (c0k >= 128) && (c0k < 1152);  // 32-aligned: all-or-none
                uint c[8];
#pragma unroll
                for (int i = 0; i < 8; ++i) {
                    const int r0i = 2 * i, r1i = 2 * i + 1;
                    const int kva = c0k + (r0i & 3) + 8 * (r0i >> 2) + 4 * hi2;
                    const int kvb = c0k + (r1i & 3) + 8 * (r1i >> 2) + 4 * hi2;
                    bool aa, ab;
                    if (bt == 0) {
                        aa = (qr == kva) | ((kva >= pe) & (qr >= kva)) | (qin & kvi);
                        ab = (qr == kvb) | ((kvb >= pe) & (qr >= kvb)) | (qin & kvi);
                    } else if (bt == 1) {
                        aa = (qr >= kva); ab = (qr >= kvb);
                    } else {
                        aa = (qr >= kva) | (kva < 1027);
                        ab = (qr >= kvb) | (kvb < 1027);
                    }
                    aa |= full_w; ab |= full_w;        // full tiles: mask forced open
                    const float sa = aa ? s[2 * i]     : -INFINITY;
                    const float sb = ab ? s[2 * i + 1] : -INFINITY;
                    const float pa = __builtin_amdgcn_exp2f(sa);   // exp2(-inf)=0
                    const float pb = __builtin_amdgcn_exp2f(sb);
                    if (i & 1) psum1 += pa + pb; else psum0 += pa + pb;
                    c[i] = pk2(pa, pb);
                }

                // ---- P half-exchange: 4x v_permlane32_swap ----
                UA A0, A1;
                {
                    uint a0 = c[0], b0 = c[2]; pl32(a0, b0);
                    uint a1 = c[1], b1 = c[3]; pl32(a1, b1);
                    A0.u[0] = a0; A0.u[1] = a1; A0.u[2] = b0; A0.u[3] = b1;
                    uint a2 = c[4], b2 = c[6]; pl32(a2, b2);
                    uint a3 = c[5], b3 = c[7]; pl32(a3, b3);
                    A1.u[0] = a2; A1.u[1] = a3; A1.u[2] = b2; A1.u[3] = b3;
                }

                // ---- PV: o[q][d] += P * V ; B-frags from V registers ----
                __builtin_amdgcn_s_setprio(1);
                o_acc[0] = __builtin_amdgcn_mfma_f32_32x32x16_bf16(A0.v, vfn[0], o_acc[0], 0, 0, 0);
                o_acc[0] = __builtin_amdgcn_mfma_f32_32x32x16_bf16(A1.v, vfn[1], o_acc[0], 0, 0, 0);
                o_acc[1] = __builtin_amdgcn_mfma_f32_32x32x16_bf16(A0.v, vfn[2], o_acc[1], 0, 0, 0);
                o_acc[1] = __builtin_amdgcn_mfma_f32_32x32x16_bf16(A1.v, vfn[3], o_acc[1], 0, 0, 0);
                __builtin_amdgcn_s_setprio(0);
            }
        }

        // ---- issue stage(i+2) LAST; ledger = 2 in-flight stages ----
        stageK((cur + 2) % 3, (kc < SS) ? kc : 0);   // dummy at tail keeps ledger uniform
        WAITVM2();                          // K(i+1) confirmed; K(i+2) in flight
        __builtin_amdgcn_s_barrier();
        __builtin_amdgcn_sched_barrier(0);
        if (kb >= SS) break;
        ka = kb; kb = kc; kc = (kc < SS) ? next_tile(kc) : SS;
        cur = (cur + 1) % 3;
    }

    // ---- finish: psum halves -> full row sums, normalize, store ----
    float psum = psum0 + psum1;
    psum += __shfl_xor(psum, 32, 64);
#pragma unroll
    for (int r = 0; r < 16; ++r) {
        const int q_loc = (r & 3) + 8 * (r >> 2) + 4 * hi2;
        const float tv = __shfl(psum, q_loc, 64);
        const float iv = 1.f / tv;
        float* dst = O + pbase + (size_t)(qw0 + q_loc) * DD + l31;
#pragma unroll
        for (int ntd = 0; ntd < 2; ++ntd)
            dst[ntd * 32] = o_acc[ntd][r] * iv;
    }
}

extern "C" void kernel_launch(void* const* d_in, const int* in_sizes, int n_in,
                              void* d_out, int out_size, void* d_ws, size_t ws_size,
                              hipStream_t stream) {
    const float* q = (const float*)d_in[0];
    const float* k = (const float*)d_in[1];
    const float* v = (const float*)d_in[2];
    float* o = (float*)d_out;

    const size_t NE = 7864320ULL;          // B*H*S*D
    ushort* Kb  = (ushort*)d_ws;
    ushort* Vtb = Kb + NE;                 // 31.5 MB workspace

    prepass8<<<dim3(5760), 256, 0, stream>>>(k, v, Kb, Vtb);
    omni_attn25<<<dim3(NITEMS), 256, 0, stream>>>(q, Kb, Vtb, o);
}

// Round 26
// 101.792 us; speedup vs baseline: 5.6702x; 1.1825x over previous
//
#include <hip/hip_runtime.h>
#include <hip/hip_bf16.h>
#include <math.h>

// OmniAttentionMechanism: flex-attention, mixed t2i/lm/mmu mask.
// B=6 (b0,b1: t2i pe=80/100; b2,b3: lm; b4,b5: mmu kv<1027), H=16, S=1280, D=64. fp32 I/O.
//
// Round 26 (on R22 green, main 93.3us): INTRA-TILE 2-CHAIN INTERLEAVE.
//   R25 refuted I-fetch (unified body +VALU = +24%) -> softmax VALU is on the
//   serial critical path, nothing overlaps it. R24 refuted TLP-shape. The nt0/nt1
//   sub-tile chains are INDEPENDENT (separate s, V-frags) but the load-bearing
//   setprio fences serialized them. Fix: one QK region (both chains interleaved,
//   8 MFMA / 2 accumulators), one softmax section (32 indep exp2), one PV region
//   (two indep 4-deep o_acc chains interleaved). Per-chain FP order unchanged.
//   Full/partial split kept (R25). Ledger/staging/sync byte-identical to R22.
//   Spill sentinel: WRITE_SIZE must stay ~31MB.

#define SS 1280
#define DD 64
#define NH 16
#define TK 64
#define QB 128
#define NITEMS 960

typedef __attribute__((ext_vector_type(8))) short bf16x8;
typedef __attribute__((ext_vector_type(16))) float f32x16;

union UA { uint u[4]; bf16x8 v; };

__device__ inline uint pk2(float a, float b) {
    union { __hip_bfloat162 h; uint u; } cv;
    cv.h = __float22bfloat162_rn(float2{a, b});   // v_cvt_pk_bf16_f32
    return cv.u;
}

// volatile: convergent cross-lane op (R17/R18 lesson)
__device__ inline void pl32(uint& a, uint& b) {
    asm volatile("v_permlane32_swap_b32 %0, %1" : "+v"(a), "+v"(b));
}

#define WAITVM2() asm volatile("s_waitcnt vmcnt(2)" ::: "memory")

// longest-first static item order
__device__ inline void decode_item(int i, int& b, int& h, int& qt) {
    if (i < 96)  { qt = 9; b = i / 16; h = i % 16; return; }                   // N=20
    i -= 96;
    if (i < 256) { b = i / 128; qt = 1 + (i % 128) / 16; h = i % 16; return; } // t2i qt1-8, N=18
    i -= 256;
    if (i < 32)  { b = 2 + i / 16; qt = 8; h = i % 16; return; }               // lm qt8, N=18
    i -= 32;
    if (i < 32)  { b = 4 + i / 16; qt = 8; h = i % 16; return; }               // mmu qt8, N=18
    i -= 32;
    if (i < 256) { b = 4 + i / 128; qt = (i % 128) / 16; h = i % 16; return; } // mmu qt0-7, N=17
    i -= 256;
    if (i < 224) { qt = 7 - i / 32; b = 2 + (i % 32) / 16; h = i % 16; return; } // lm qt7..1
    i -= 224;
    if (i < 32)  { b = 2 + i / 16; qt = 0; h = i % 16; return; }               // lm qt0, N=2
    i -= 32;
    b = i / 16; qt = 0; h = i % 16;                                            // t2i qt0, N=2
}

// ============ fused prepass: K->bf16 (gx<3840) | V->Vt[d][kv] bf16 (gx>=3840) ============
__global__ __launch_bounds__(256) void prepass8(
    const float* __restrict__ K, const float* __restrict__ V,
    ushort* __restrict__ Kb, ushort* __restrict__ Vtb)
{
    const int gx = blockIdx.x;
    const int t  = threadIdx.x;
    if (gx < 3840) {
        const size_t e = ((size_t)gx * 256 + t) * 8;
        const float4 a = *(const float4*)(K + e);
        const float4 c = *(const float4*)(K + e + 4);
        UA u;
        u.u[0] = pk2(a.x, a.y); u.u[1] = pk2(a.z, a.w);
        u.u[2] = pk2(c.x, c.y); u.u[3] = pk2(c.z, c.w);
        *(bf16x8*)(Kb + e) = u.v;
    } else {
        const int g   = gx - 3840;
        const int kvt = g % 20;
        const int p   = g / 20;
        __shared__ float T[64 * 67];
#pragma unroll
        for (int i = 0; i < 16; ++i) {
            const int idx = t + 256 * i;
            T[(idx >> 6) * 67 + (idx & 63)] = V[(size_t)p * (SS * DD) + (size_t)(kvt * 64) * DD + idx];
        }
        __syncthreads();
        ushort* dst = Vtb + (size_t)p * (DD * SS) + kvt * 64;
#pragma unroll
        for (int i = 0; i < 2; ++i) {
            const int c0 = t + 256 * i;
            const int d = c0 >> 3, kc = c0 & 7;
            UA u;
#pragma unroll
            for (int j = 0; j < 4; ++j)
                u.u[j] = pk2(T[(kc * 8 + 2 * j) * 67 + d], T[(kc * 8 + 2 * j + 1) * 67 + d]);
            *(bf16x8*)(dst + (size_t)d * SS + kc * 8) = u.v;
        }
    }
}

// ============================ main attention kernel ============================
__global__ __launch_bounds__(256) void omni_attn26(
    const float* __restrict__ Q, const ushort* __restrict__ Kb,
    const ushort* __restrict__ Vtb, float* __restrict__ O)
{
    int b, h, qt;
    decode_item(blockIdx.x, b, h, qt);     // longest-first dispatch order

    const int t   = threadIdx.x;
    const int w   = t >> 6;
    const int l   = t & 63;
    const int l31 = l & 31;
    const int hi2 = l >> 5;

    const int p   = b * NH + h;
    const int qb0 = qt * QB;
    const int qw0 = qb0 + w * 32;
    const int qr  = qw0 + l31;
    const size_t pbase = (size_t)p * (SS * DD);

    const int bt = (b < 2) ? 0 : (b < 4) ? 1 : 2;
    const int pe = (b == 0) ? 80 : (b == 1) ? 100 : 0;
    const int qmax_blk = qb0 + QB - 1;
    const int qmax_w   = qw0 + 31;
    const bool blk_img = (qb0 + QB - 1 >= 128) && (qb0 < 1152);
    const bool w_img   = (qw0 >= 128) && (qw0 < 1152);
    const bool qin     = (qr >= 128) && (qr < 1152);

    __shared__ char smem[3 * 8192];        // 3 K-only buffers

    const float scale = 0.125f * 1.44269504088896340736f;

    int koff[2];
#pragma unroll
    for (int rd = 0; rd < 2; ++rd) {
        const int ci  = rd * 256 + w * 64 + l;
        const int row = ci >> 3, cc = ci & 7;
        koff[rd] = row * DD + (cc ^ (row & 7)) * 8;
    }

    // ---- Q fragments, scale folded in (p = exp2(K·(Q*scale))) ----
    bf16x8 qf[4];
#pragma unroll
    for (int ks = 0; ks < 4; ++ks) {
        const float* src = Q + pbase + (size_t)qr * DD + ks * 16 + hi2 * 8;
        const float4 a = *(const float4*)(src);
        const float4 c = *(const float4*)(src + 4);
        UA u;
        u.u[0] = pk2(a.x * scale, a.y * scale); u.u[1] = pk2(a.z * scale, a.w * scale);
        u.u[2] = pk2(c.x * scale, c.y * scale); u.u[3] = pk2(c.z * scale, c.w * scale);
        qf[ks] = u.v;
    }

    f32x16 o_acc[2];
#pragma unroll
    for (int ntd = 0; ntd < 2; ++ntd)
#pragma unroll
        for (int r = 0; r < 16; ++r) o_acc[ntd][r] = 0.f;
    float psum0 = 0.f, psum1 = 0.f;

    auto need_blk = [&](int k0) -> bool {
        if (bt == 0) return (k0 <= qmax_blk) || (blk_img && k0 >= 128 && k0 < 1152);
        if (bt == 1) return (k0 <= qmax_blk);
        return (k0 <= qmax_blk) || (k0 < 1027);
    };
    auto next_tile = [&](int k) -> int {
        k += TK;
        while (k < SS && !need_blk(k)) k += TK;
        return k;
    };
    auto stageK = [&](int bsel, int k0s) {
        char* buf = smem + bsel * 8192;
        const ushort* Kp = Kb + pbase + (size_t)k0s * DD;
#pragma unroll
        for (int rd = 0; rd < 2; ++rd) {
            char* lb = buf + (rd * 256 + w * 64) * 16;
            __builtin_amdgcn_global_load_lds(
                (const __attribute__((address_space(1))) void*)(Kp + koff[rd]),
                (__attribute__((address_space(3))) void*)lb, 16, 0, 0);
        }
    };

    const ushort* vrow0 = Vtb + pbase + (size_t)l31 * SS + hi2 * 8;
    const ushort* vrow1 = vrow0 + 32 * SS;

    // ---- 3-buffer, 2-deep pipeline; stage issued post-compute; vmcnt(2)/tile ----
    int ka = 0, cur = 0;
    int kb = next_tile(0);
    int kc = (kb < SS) ? next_tile(kb) : SS;
    stageK(0, ka);
    stageK(1, kb);
    WAITVM2();
    __builtin_amdgcn_s_barrier();
    __builtin_amdgcn_sched_barrier(0);

    while (true) {
        const int k0 = ka;
        const bool kv_img = (k0 >= 128) && (k0 < 1152);
        bool need_w, full_w;
        if (bt == 0) {
            need_w = (k0 <= qmax_w) || (w_img && kv_img);
            full_w = ((k0 >= pe) && (k0 + 63 <= qw0)) || (w_img && kv_img);
        } else if (bt == 1) {
            need_w = (k0 <= qmax_w);
            full_w = (k0 + 63 <= qw0);
        } else {
            need_w = (k0 <= qmax_w) || (k0 < 1027);
            full_w = (k0 + 63 <= qw0) || (k0 + 63 < 1027);
        }

        if (need_w) {
            char* cbuf = smem + cur * 8192;

            // ---- V fragments for BOTH kv halves (8 x bf16x8 = 32 regs) ----
            bf16x8 vfn[8];
            vfn[0] = *(const bf16x8*)(vrow0 + k0);
            vfn[1] = *(const bf16x8*)(vrow0 + k0 + 16);
            vfn[2] = *(const bf16x8*)(vrow1 + k0);
            vfn[3] = *(const bf16x8*)(vrow1 + k0 + 16);
            vfn[4] = *(const bf16x8*)(vrow0 + k0 + 32);
            vfn[5] = *(const bf16x8*)(vrow0 + k0 + 48);
            vfn[6] = *(const bf16x8*)(vrow1 + k0 + 32);
            vfn[7] = *(const bf16x8*)(vrow1 + k0 + 48);

            // ---- QK^T: BOTH nt chains in ONE region, interleaved ----
            f32x16 sA, sB;
#pragma unroll
            for (int r = 0; r < 16; ++r) { sA[r] = 0.f; sB[r] = 0.f; }
            __builtin_amdgcn_s_setprio(1);
#pragma unroll
            for (int ksd = 0; ksd < 4; ++ksd) {
                const int rowA = l31;
                int offA = rowA * 128 + ksd * 32 + hi2 * 16;
                offA ^= (rowA & 7) << 4;
                const bf16x8 kfA = *(const bf16x8*)(cbuf + offA);
                sA = __builtin_amdgcn_mfma_f32_32x32x16_bf16(kfA, qf[ksd], sA, 0, 0, 0);
                const int rowB = 32 + l31;
                int offB = rowB * 128 + ksd * 32 + hi2 * 16;
                offB ^= (rowB & 7) << 4;
                const bf16x8 kfB = *(const bf16x8*)(cbuf + offB);
                sB = __builtin_amdgcn_mfma_f32_32x32x16_bf16(kfB, qf[ksd], sB, 0, 0, 0);
            }
            __builtin_amdgcn_s_setprio(0);

            // ---- softmax for BOTH halves (32 independent exp2) ----
            const bool kviA = (k0 >= 128) && (k0 < 1152);
            const bool kviB = (k0 + 32 >= 128) && (k0 + 32 < 1152);
            uint cA[8], cB[8];
            if (full_w) {
#pragma unroll
                for (int i = 0; i < 8; ++i) {
                    const float pa = __builtin_amdgcn_exp2f(sA[2 * i]);
                    const float pb = __builtin_amdgcn_exp2f(sA[2 * i + 1]);
                    const float pc = __builtin_amdgcn_exp2f(sB[2 * i]);
                    const float pd = __builtin_amdgcn_exp2f(sB[2 * i + 1]);
                    if (i & 1) psum1 += (pa + pb) + (pc + pd);
                    else       psum0 += (pa + pb) + (pc + pd);
                    cA[i] = pk2(pa, pb);
                    cB[i] = pk2(pc, pd);
                }
            } else {
#pragma unroll
                for (int i = 0; i < 8; ++i) {
                    const int r0i = 2 * i, r1i = 2 * i + 1;
                    const int base0 = (r0i & 3) + 8 * (r0i >> 2) + 4 * hi2;
                    const int base1 = (r1i & 3) + 8 * (r1i >> 2) + 4 * hi2;
                    const int kvaA = k0 + base0, kvbA = k0 + base1;
                    const int kvaB = k0 + 32 + base0, kvbB = k0 + 32 + base1;
                    bool aa, ab, ba, bb;
                    if (bt == 0) {
                        aa = (qr == kvaA) | ((kvaA >= pe) & (qr >= kvaA)) | (qin & kviA);
                        ab = (qr == kvbA) | ((kvbA >= pe) & (qr >= kvbA)) | (qin & kviA);
                        ba = (qr == kvaB) | ((kvaB >= pe) & (qr >= kvaB)) | (qin & kviB);
                        bb = (qr == kvbB) | ((kvbB >= pe) & (qr >= kvbB)) | (qin & kviB);
                    } else if (bt == 1) {
                        aa = (qr >= kvaA); ab = (qr >= kvbA);
                        ba = (qr >= kvaB); bb = (qr >= kvbB);
                    } else {
                        aa = (qr >= kvaA) | (kvaA < 1027);
                        ab = (qr >= kvbA) | (kvbA < 1027);
                        ba = (qr >= kvaB) | (kvaB < 1027);
                        bb = (qr >= kvbB) | (kvbB < 1027);
                    }
                    const float pa = aa ? __builtin_amdgcn_exp2f(sA[2 * i])     : 0.f;
                    const float pb = ab ? __builtin_amdgcn_exp2f(sA[2 * i + 1]) : 0.f;
                    const float pc = ba ? __builtin_amdgcn_exp2f(sB[2 * i])     : 0.f;
                    const float pd = bb ? __builtin_amdgcn_exp2f(sB[2 * i + 1]) : 0.f;
                    if (i & 1) psum1 += (pa + pb) + (pc + pd);
                    else       psum0 += (pa + pb) + (pc + pd);
                    cA[i] = pk2(pa, pb);
                    cB[i] = pk2(pc, pd);
                }
            }

            // ---- P half-exchange: 8x v_permlane32_swap (both halves) ----
            UA A0a, A1a, A0b, A1b;
            {
                uint a0 = cA[0], b0 = cA[2]; pl32(a0, b0);
                uint a1 = cA[1], b1 = cA[3]; pl32(a1, b1);
                A0a.u[0] = a0; A0a.u[1] = a1; A0a.u[2] = b0; A0a.u[3] = b1;
                uint a2 = cA[4], b2 = cA[6]; pl32(a2, b2);
                uint a3 = cA[5], b3 = cA[7]; pl32(a3, b3);
                A1a.u[0] = a2; A1a.u[1] = a3; A1a.u[2] = b2; A1a.u[3] = b3;
                uint a4 = cB[0], b4 = cB[2]; pl32(a4, b4);
                uint a5 = cB[1], b5 = cB[3]; pl32(a5, b5);
                A0b.u[0] = a4; A0b.u[1] = a5; A0b.u[2] = b4; A0b.u[3] = b5;
                uint a6 = cB[4], b6 = cB[6]; pl32(a6, b6);
                uint a7 = cB[5], b7 = cB[7]; pl32(a7, b7);
                A1b.u[0] = a6; A1b.u[1] = a7; A1b.u[2] = b6; A1b.u[3] = b7;
            }

            // ---- PV: ONE region, two independent 4-deep o_acc chains interleaved.
            //      Per-chain accumulation order identical to R22 (bitwise-safe). ----
            __builtin_amdgcn_s_setprio(1);
            o_acc[0] = __builtin_amdgcn_mfma_f32_32x32x16_bf16(A0a.v, vfn[0], o_acc[0], 0, 0, 0);
            o_acc[1] = __builtin_amdgcn_mfma_f32_32x32x16_bf16(A0a.v, vfn[2], o_acc[1], 0, 0, 0);
            o_acc[0] = __builtin_amdgcn_mfma_f32_32x32x16_bf16(A1a.v, vfn[1], o_acc[0], 0, 0, 0);
            o_acc[1] = __builtin_amdgcn_mfma_f32_32x32x16_bf16(A1a.v, vfn[3], o_acc[1], 0, 0, 0);
            o_acc[0] = __builtin_amdgcn_mfma_f32_32x32x16_bf16(A0b.v, vfn[4], o_acc[0], 0, 0, 0);
            o_acc[1] = __builtin_amdgcn_mfma_f32_32x32x16_bf16(A0b.v, vfn[6], o_acc[1], 0, 0, 0);
            o_acc[0] = __builtin_amdgcn_mfma_f32_32x32x16_bf16(A1b.v, vfn[5], o_acc[0], 0, 0, 0);
            o_acc[1] = __builtin_amdgcn_mfma_f32_32x32x16_bf16(A1b.v, vfn[7], o_acc[1], 0, 0, 0);
            __builtin_amdgcn_s_setprio(0);
        }

        // ---- issue stage(i+2) LAST; ledger = 2 in-flight stages ----
        stageK((cur + 2) % 3, (kc < SS) ? kc : 0);
        WAITVM2();
        __builtin_amdgcn_s_barrier();
        __builtin_amdgcn_sched_barrier(0);
        if (kb >= SS) break;
        ka = kb; kb = kc; kc = (kc < SS) ? next_tile(kc) : SS;
        cur = (cur + 1) % 3;
    }

    // ---- finish: psum halves -> full row sums, normalize, store ----
    float psum = psum0 + psum1;
    psum += __shfl_xor(psum, 32, 64);
#pragma unroll
    for (int r = 0; r < 16; ++r) {
        const int q_loc = (r & 3) + 8 * (r >> 2) + 4 * hi2;
        const float tv = __shfl(psum, q_loc, 64);
        const float iv = 1.f / tv;
        float* dst = O + pbase + (size_t)(qw0 + q_loc) * DD + l31;
#pragma unroll
        for (int ntd = 0; ntd < 2; ++ntd)
            dst[ntd * 32] = o_acc[ntd][r] * iv;
    }
}

extern "C" void kernel_launch(void* const* d_in, const int* in_sizes, int n_in,
                              void* d_out, int out_size, void* d_ws, size_t ws_size,
                              hipStream_t stream) {
    const float* q = (const float*)d_in[0];
    const float* k = (const float*)d_in[1];
    const float* v = (const float*)d_in[2];
    float* o = (float*)d_out;

    const size_t NE = 7864320ULL;          // B*H*S*D
    ushort* Kb  = (ushort*)d_ws;
    ushort* Vtb = Kb + NE;                 // 31.5 MB workspace

    prepass8<<<dim3(5760), 256, 0, stream>>>(k, v, Kb, Vtb);
    omni_attn26<<<dim3(NITEMS), 256, 0, stream>>>(q, Kb, Vtb, o);
}